// Round 1
// baseline (848.774 us; speedup 1.0000x reference)
//
#include <hip/hip_runtime.h>
#include <math.h>

// Problem constants (setup_inputs): B=4, N=2048, C=512, H=8, Dh=64
#define BB 4
#define NN 2048
#define CC 512
#define HH 8
#define DH 64
#define MM (BB*NN)          // 8192 rows
#define QKV_N (3*CC)        // 1536

// ---------------------------------------------------------------------------
// Kernel 1: QKV GEMM (M=8192, N=1536, K=512) + fused RoPE epilogue.
// Writes q,k,v in (B,H,N,Dh) layout into workspace.
// 64x64 tile, BK=16, 256 threads, 4x4 micro-tile.
// ---------------------------------------------------------------------------
__global__ __launch_bounds__(256) void qkv_rope_kernel(
    const float* __restrict__ x, const float* __restrict__ Wqkv,
    const float* __restrict__ times, const int* __restrict__ nclsp,
    float* __restrict__ qo, float* __restrict__ ko, float* __restrict__ vo)
{
    __shared__ float As[16][68];   // [k][m]
    __shared__ float Bs[16][68];   // [k][n]
    const int m0 = blockIdx.x * 64;
    const int n0 = blockIdx.y * 64;
    const int tid = threadIdx.x;
    const int ty = tid >> 4, tx = tid & 15;
    const int lr = tid >> 2;          // 0..63 row within tile
    const int lc = (tid & 3) << 2;    // 0,4,8,12: k-chunk

    float acc[4][4] = {};
    const float* xrow = x    + (size_t)(m0 + lr) * CC + lc;
    const float* wrow = Wqkv + (size_t)(n0 + lr) * CC + lc;

    for (int k0 = 0; k0 < CC; k0 += 16) {
        float4 a4 = *(const float4*)(xrow + k0);
        float4 b4 = *(const float4*)(wrow + k0);
        As[lc+0][lr] = a4.x; As[lc+1][lr] = a4.y;
        As[lc+2][lr] = a4.z; As[lc+3][lr] = a4.w;
        Bs[lc+0][lr] = b4.x; Bs[lc+1][lr] = b4.y;
        Bs[lc+2][lr] = b4.z; Bs[lc+3][lr] = b4.w;
        __syncthreads();
        #pragma unroll
        for (int kk = 0; kk < 16; ++kk) {
            float4 av = *(const float4*)&As[kk][ty << 2];
            float4 bv = *(const float4*)&Bs[kk][tx << 2];
            float ar[4] = {av.x, av.y, av.z, av.w};
            float br[4] = {bv.x, bv.y, bv.z, bv.w};
            #pragma unroll
            for (int r = 0; r < 4; ++r)
                #pragma unroll
                for (int c = 0; c < 4; ++c)
                    acc[r][c] = fmaf(ar[r], br[c], acc[r][c]);
        }
        __syncthreads();
    }

    // Epilogue: whole block lies in one of q/k/v and one head (tiles are
    // 64-wide and head dim = 64).
    const int which = n0 >> 9;           // 0=q, 1=k, 2=v
    const int h     = (n0 & 511) >> 6;
    const int ncls  = *nclsp;
    float* dst = (which == 0) ? qo : (which == 1) ? ko : vo;

    #pragma unroll
    for (int r = 0; r < 4; ++r) {
        const int m = m0 + (ty << 2) + r;
        const int b = m >> 11;           // / 2048
        const int n = m & (NN - 1);
        float* outp = dst + ((size_t)((b << 3) + h) * NN + n) * DH + (tx << 2);
        float4 o;
        if (which == 2 || n < ncls) {
            o = make_float4(acc[r][0], acc[r][1], acc[r][2], acc[r][3]);
        } else {
            const float pos = rintf(times[m] * 30.0f);  // MAX_FPS
            float res[4];
            #pragma unroll
            for (int p = 0; p < 2; ++p) {
                const int j = (tx << 1) + p;            // freq index d/2
                const float invf = exp2f((float)j * (-13.287712379549449f / 32.0f));
                float s, co;
                sincosf(pos * invf, &s, &co);
                const float x0 = acc[r][2*p];
                const float x1 = acc[r][2*p + 1];
                res[2*p]     = x0 * co - x1 * s;
                res[2*p + 1] = x0 * s  + x1 * co;
            }
            o = make_float4(res[0], res[1], res[2], res[3]);
        }
        *(float4*)outp = o;
    }
}

// ---------------------------------------------------------------------------
// Kernel 2: flash-style attention. One block per (bh, 64-row q tile).
// 256 threads, 4x4 micro-tile, online softmax. fp32.
// ---------------------------------------------------------------------------
__global__ __launch_bounds__(256) void attn_kernel(
    const float* __restrict__ qg, const float* __restrict__ kg,
    const float* __restrict__ vg, const float* __restrict__ mask,
    float* __restrict__ out)
{
    __shared__ float Qs[64][68];   // [q_row][d]   natural
    __shared__ float Ks[64][68];   // [d][key]     transposed
    __shared__ float Vs[64][68];   // [key][d]     natural
    __shared__ float Ps[64][68];   // [q_row][key] natural
    __shared__ float Ms[64];

    const int qt  = blockIdx.x;          // 0..31
    const int bh  = blockIdx.y;          // 0..31
    const int b   = bh >> 3;
    const int h   = bh & 7;
    const int tid = threadIdx.x;
    const int ty = tid >> 4, tx = tid & 15;
    const int lr = tid >> 2;             // 0..63
    const int lq = (tid & 3) << 4;       // 0,16,32,48

    const float* qbase = qg + ((size_t)bh * NN + qt * 64) * DH;
    const float* kbase = kg + (size_t)bh * NN * DH;
    const float* vbase = vg + (size_t)bh * NN * DH;

    // Load Q tile (natural layout)
    #pragma unroll
    for (int i = 0; i < 4; ++i) {
        float4 t = *(const float4*)(qbase + lr * DH + lq + i * 4);
        *(float4*)&Qs[lr][lq + i * 4] = t;
    }

    float O[4][4] = {};
    float m_run[4], l_run[4];
    #pragma unroll
    for (int r = 0; r < 4; ++r) { m_run[r] = -INFINITY; l_run[r] = 0.0f; }
    const float scale = 0.125f;   // 1/sqrt(64)

    for (int kt = 0; kt < NN / 64; ++kt) {
        __syncthreads();   // previous tile's Ps/Vs reads done; Q visible on kt=0
        #pragma unroll
        for (int i = 0; i < 4; ++i) {
            float4 t = *(const float4*)(kbase + (size_t)(kt * 64 + lr) * DH + lq + i * 4);
            Ks[lq + i*4 + 0][lr] = t.x; Ks[lq + i*4 + 1][lr] = t.y;
            Ks[lq + i*4 + 2][lr] = t.z; Ks[lq + i*4 + 3][lr] = t.w;
            float4 u = *(const float4*)(vbase + (size_t)(kt * 64 + lr) * DH + lq + i * 4);
            *(float4*)&Vs[lr][lq + i * 4] = u;
        }
        if (tid < 16)
            *(float4*)&Ms[tid << 2] = *(const float4*)(mask + (size_t)b * NN + kt * 64 + (tid << 2));
        __syncthreads();

        // S = Q K^T (4x4 per thread)
        float S[4][4] = {};
        #pragma unroll 8
        for (int kk = 0; kk < 64; ++kk) {
            float a0 = Qs[(ty << 2) + 0][kk];
            float a1 = Qs[(ty << 2) + 1][kk];
            float a2 = Qs[(ty << 2) + 2][kk];
            float a3 = Qs[(ty << 2) + 3][kk];
            float4 bv = *(const float4*)&Ks[kk][tx << 2];
            float br[4] = {bv.x, bv.y, bv.z, bv.w};
            #pragma unroll
            for (int c = 0; c < 4; ++c) {
                S[0][c] = fmaf(a0, br[c], S[0][c]);
                S[1][c] = fmaf(a1, br[c], S[1][c]);
                S[2][c] = fmaf(a2, br[c], S[2][c]);
                S[3][c] = fmaf(a3, br[c], S[3][c]);
            }
        }

        // scale + mask, online softmax
        float mx[4], rs[4], alpha[4];
        #pragma unroll
        for (int r = 0; r < 4; ++r) {
            #pragma unroll
            for (int c = 0; c < 4; ++c)
                S[r][c] = S[r][c] * scale + Ms[(tx << 2) + c];
            mx[r] = fmaxf(fmaxf(S[r][0], S[r][1]), fmaxf(S[r][2], S[r][3]));
        }
        #pragma unroll
        for (int off = 1; off < 16; off <<= 1) {
            #pragma unroll
            for (int r = 0; r < 4; ++r)
                mx[r] = fmaxf(mx[r], __shfl_xor(mx[r], off));
        }
        #pragma unroll
        for (int r = 0; r < 4; ++r) {
            float mnew = fmaxf(m_run[r], mx[r]);
            alpha[r] = __expf(m_run[r] - mnew);   // first tile: exp(-inf)=0
            m_run[r] = mnew;
            rs[r] = 0.0f;
            #pragma unroll
            for (int c = 0; c < 4; ++c) {
                S[r][c] = __expf(S[r][c] - mnew);
                rs[r] += S[r][c];
            }
        }
        #pragma unroll
        for (int off = 1; off < 16; off <<= 1) {
            #pragma unroll
            for (int r = 0; r < 4; ++r)
                rs[r] += __shfl_xor(rs[r], off);
        }
        #pragma unroll
        for (int r = 0; r < 4; ++r) {
            l_run[r] = l_run[r] * alpha[r] + rs[r];
            #pragma unroll
            for (int c = 0; c < 4; ++c) O[r][c] *= alpha[r];
            *(float4*)&Ps[(ty << 2) + r][tx << 2] =
                make_float4(S[r][0], S[r][1], S[r][2], S[r][3]);
        }
        __syncthreads();

        // O += P V
        #pragma unroll 8
        for (int kk = 0; kk < 64; ++kk) {
            float p0 = Ps[(ty << 2) + 0][kk];
            float p1 = Ps[(ty << 2) + 1][kk];
            float p2 = Ps[(ty << 2) + 2][kk];
            float p3 = Ps[(ty << 2) + 3][kk];
            float4 vv = *(const float4*)&Vs[kk][tx << 2];
            float vr[4] = {vv.x, vv.y, vv.z, vv.w};
            #pragma unroll
            for (int c = 0; c < 4; ++c) {
                O[0][c] = fmaf(p0, vr[c], O[0][c]);
                O[1][c] = fmaf(p1, vr[c], O[1][c]);
                O[2][c] = fmaf(p2, vr[c], O[2][c]);
                O[3][c] = fmaf(p3, vr[c], O[3][c]);
            }
        }
    }

    // Normalize and write (B, N, C) layout
    #pragma unroll
    for (int r = 0; r < 4; ++r) {
        const float inv = 1.0f / l_run[r];
        const int n = qt * 64 + (ty << 2) + r;
        float4 o = make_float4(O[r][0] * inv, O[r][1] * inv,
                               O[r][2] * inv, O[r][3] * inv);
        *(float4*)(out + ((size_t)b * NN + n) * CC + h * DH + (tx << 2)) = o;
    }
}

// ---------------------------------------------------------------------------
// Kernel 3: output projection GEMM (M=8192, N=512, K=512) + bias.
// ---------------------------------------------------------------------------
__global__ __launch_bounds__(256) void proj_kernel(
    const float* __restrict__ a, const float* __restrict__ W,
    const float* __restrict__ bias, float* __restrict__ out)
{
    __shared__ float As[16][68];
    __shared__ float Bs[16][68];
    const int m0 = blockIdx.x * 64;
    const int n0 = blockIdx.y * 64;
    const int tid = threadIdx.x;
    const int ty = tid >> 4, tx = tid & 15;
    const int lr = tid >> 2;
    const int lc = (tid & 3) << 2;

    float acc[4][4] = {};
    const float* arow = a + (size_t)(m0 + lr) * CC + lc;
    const float* wrow = W + (size_t)(n0 + lr) * CC + lc;

    for (int k0 = 0; k0 < CC; k0 += 16) {
        float4 a4 = *(const float4*)(arow + k0);
        float4 b4 = *(const float4*)(wrow + k0);
        As[lc+0][lr] = a4.x; As[lc+1][lr] = a4.y;
        As[lc+2][lr] = a4.z; As[lc+3][lr] = a4.w;
        Bs[lc+0][lr] = b4.x; Bs[lc+1][lr] = b4.y;
        Bs[lc+2][lr] = b4.z; Bs[lc+3][lr] = b4.w;
        __syncthreads();
        #pragma unroll
        for (int kk = 0; kk < 16; ++kk) {
            float4 av = *(const float4*)&As[kk][ty << 2];
            float4 bv = *(const float4*)&Bs[kk][tx << 2];
            float ar[4] = {av.x, av.y, av.z, av.w};
            float br[4] = {bv.x, bv.y, bv.z, bv.w};
            #pragma unroll
            for (int r = 0; r < 4; ++r)
                #pragma unroll
                for (int c = 0; c < 4; ++c)
                    acc[r][c] = fmaf(ar[r], br[c], acc[r][c]);
        }
        __syncthreads();
    }

    float4 bb = *(const float4*)(bias + n0 + (tx << 2));
    #pragma unroll
    for (int r = 0; r < 4; ++r) {
        const int m = m0 + (ty << 2) + r;
        float4 o = make_float4(acc[r][0] + bb.x, acc[r][1] + bb.y,
                               acc[r][2] + bb.z, acc[r][3] + bb.w);
        *(float4*)(out + (size_t)m * CC + n0 + (tx << 2)) = o;
    }
}

// ---------------------------------------------------------------------------
extern "C" void kernel_launch(void* const* d_in, const int* in_sizes, int n_in,
                              void* d_out, int out_size, void* d_ws, size_t ws_size,
                              hipStream_t stream)
{
    const float* x     = (const float*)d_in[0];
    const float* mask  = (const float*)d_in[1];
    const float* times = (const float*)d_in[2];
    const float* Wqkv  = (const float*)d_in[3];
    const float* Wproj = (const float*)d_in[4];
    const float* bproj = (const float*)d_in[5];
    const int*   ncls  = (const int*)d_in[6];
    float* out = (float*)d_out;

    float* ws = (float*)d_ws;
    const size_t per = (size_t)BB * HH * NN * DH;   // 4,194,304 floats
    float* q  = ws;
    float* k  = ws + per;
    float* v  = ws + 2 * per;
    float* ao = ws + 3 * per;                       // attention out (B,N,C)

    qkv_rope_kernel<<<dim3(MM / 64, QKV_N / 64), 256, 0, stream>>>(
        x, Wqkv, times, ncls, q, k, v);
    attn_kernel<<<dim3(NN / 64, BB * HH), 256, 0, stream>>>(
        q, k, v, mask, ao);
    proj_kernel<<<dim3(MM / 64, CC / 64), 256, 0, stream>>>(
        ao, Wproj, bproj, out);
}

// Round 2
// 380.222 us; speedup vs baseline: 2.2323x; 2.2323x over previous
//
#include <hip/hip_runtime.h>
#include <math.h>

// Problem constants (setup_inputs): B=4, N=2048, C=512, H=8, Dh=64
#define BB 4
#define NN 2048
#define CC 512
#define HH 8
#define DH 64
#define MM (BB*NN)          // 8192 rows
#define QKV_N (3*CC)        // 1536

typedef _Float16 f16;
typedef __attribute__((ext_vector_type(4))) _Float16 f16x4;
typedef __attribute__((ext_vector_type(8))) _Float16 f16x8;
typedef __attribute__((ext_vector_type(4))) float f32x4;

#define L2E 1.4426950408889634f

// ---------------------------------------------------------------------------
// Kernel 1: QKV GEMM (M=8192, N=1536, K=512) fp32 + fused RoPE epilogue.
// Writes q,k as fp16 (B,H,N,Dh); v as fp16 TRANSPOSED (B,H,Dh,N).
// ---------------------------------------------------------------------------
__global__ __launch_bounds__(256) void qkv_rope_kernel(
    const float* __restrict__ x, const float* __restrict__ Wqkv,
    const float* __restrict__ times, const int* __restrict__ nclsp,
    f16* __restrict__ qo, f16* __restrict__ ko, f16* __restrict__ vto)
{
    __shared__ float As[16][68];   // [k][m]
    __shared__ float Bs[16][68];   // [k][n]
    const int m0 = blockIdx.x * 64;
    const int n0 = blockIdx.y * 64;
    const int tid = threadIdx.x;
    const int ty = tid >> 4, tx = tid & 15;
    const int lr = tid >> 2;          // 0..63 row within tile
    const int lc = (tid & 3) << 2;    // 0,4,8,12: k-chunk

    float acc[4][4] = {};
    const float* xrow = x    + (size_t)(m0 + lr) * CC + lc;
    const float* wrow = Wqkv + (size_t)(n0 + lr) * CC + lc;

    for (int k0 = 0; k0 < CC; k0 += 16) {
        float4 a4 = *(const float4*)(xrow + k0);
        float4 b4 = *(const float4*)(wrow + k0);
        As[lc+0][lr] = a4.x; As[lc+1][lr] = a4.y;
        As[lc+2][lr] = a4.z; As[lc+3][lr] = a4.w;
        Bs[lc+0][lr] = b4.x; Bs[lc+1][lr] = b4.y;
        Bs[lc+2][lr] = b4.z; Bs[lc+3][lr] = b4.w;
        __syncthreads();
        #pragma unroll
        for (int kk = 0; kk < 16; ++kk) {
            float4 av = *(const float4*)&As[kk][ty << 2];
            float4 bv = *(const float4*)&Bs[kk][tx << 2];
            float ar[4] = {av.x, av.y, av.z, av.w};
            float br[4] = {bv.x, bv.y, bv.z, bv.w};
            #pragma unroll
            for (int r = 0; r < 4; ++r)
                #pragma unroll
                for (int c = 0; c < 4; ++c)
                    acc[r][c] = fmaf(ar[r], br[c], acc[r][c]);
        }
        __syncthreads();
    }

    // Epilogue. Tiles are 64-wide and head dim = 64, so the whole block lies
    // in one of q/k/v and one head.
    const int which = n0 >> 9;           // 0=q, 1=k, 2=v
    const int h     = (n0 & 511) >> 6;
    const int b     = m0 >> 11;          // batch (same for all 64 rows)
    const int nloc0 = m0 & (NN - 1);

    if (which == 2) {
        // v: write transposed (B,H,Dh,N), packing the 4 m-rows (consecutive n)
        #pragma unroll
        for (int c = 0; c < 4; ++c) {
            const int d = (tx << 2) + c;
            f16x4 pk = { (f16)acc[0][c], (f16)acc[1][c],
                         (f16)acc[2][c], (f16)acc[3][c] };
            *(f16x4*)(vto + ((size_t)((b << 3) + h) * DH + d) * NN
                          + nloc0 + (ty << 2)) = pk;
        }
        return;
    }

    const int ncls = *nclsp;
    f16* dst = (which == 0) ? qo : ko;

    #pragma unroll
    for (int r = 0; r < 4; ++r) {
        const int m = m0 + (ty << 2) + r;
        const int n = m & (NN - 1);
        f16* outp = dst + ((size_t)((b << 3) + h) * NN + n) * DH + (tx << 2);
        float res[4];
        if (n < ncls) {
            res[0]=acc[r][0]; res[1]=acc[r][1]; res[2]=acc[r][2]; res[3]=acc[r][3];
        } else {
            const float pos = rintf(times[m] * 30.0f);  // MAX_FPS
            #pragma unroll
            for (int p = 0; p < 2; ++p) {
                const int j = (tx << 1) + p;            // freq index d/2
                const float invf = exp2f((float)j * (-13.287712379549449f / 32.0f));
                float s, co;
                sincosf(pos * invf, &s, &co);
                const float x0 = acc[r][2*p];
                const float x1 = acc[r][2*p + 1];
                res[2*p]     = x0 * co - x1 * s;
                res[2*p + 1] = x0 * s  + x1 * co;
            }
        }
        f16x4 o4 = { (f16)res[0], (f16)res[1], (f16)res[2], (f16)res[3] };
        *(f16x4*)outp = o4;
    }
}

// ---------------------------------------------------------------------------
// Kernel 2: fp16-MFMA flash attention.
// Grid: x = bh (32, so bh%8 pins a head-group per XCD), y = q-tile (16).
// Block: 256 threads = 4 waves; each wave owns 32 q rows (Q-tile 128).
// Computes S^T = K·Q^T per 64-key tile (softmax reduction is in-lane + 2
// cross-quad shuffles), P^T round-trips LDS as b64 packs, then O = P·V.
// ---------------------------------------------------------------------------
__global__ __launch_bounds__(256, 2) void attn_kernel(
    const f16* __restrict__ qg, const f16* __restrict__ kg,
    const f16* __restrict__ vtg, const float* __restrict__ mask,
    float* __restrict__ out)
{
    __shared__ f16 Kh[64][72];      // [key][d]
    __shared__ f16 Vt[64][72];      // [d][key]
    __shared__ f16 Pt[4][32][72];   // per-wave [q][key]
    __shared__ float Msk[64];       // mask*log2e for current key tile
    __shared__ float Brd[4][32];    // per-wave alpha / l broadcast

    const int bh  = blockIdx.x;          // 0..31
    const int qt  = blockIdx.y;          // 0..15
    const int b   = bh >> 3;
    const int h   = bh & 7;
    const int tid = threadIdx.x;
    const int w    = tid >> 6;
    const int lane = tid & 63;
    const int l15  = lane & 15;
    const int quad = lane >> 4;

    const f16* qbase  = qg  + ((size_t)bh * NN + qt * 128 + w * 32) * DH;
    const f16* kbase  = kg  + (size_t)bh * NN * DH;
    const f16* vtbase = vtg + (size_t)bh * DH * NN;

    // Q B-fragments: persistent across the whole K loop.
    // B[n=q][k=d]: lane holds q = 16*ni + l15, d = kc*32 + quad*8 .. +8
    f16x8 Bq[2][2];
    #pragma unroll
    for (int ni = 0; ni < 2; ++ni)
        #pragma unroll
        for (int kc = 0; kc < 2; ++kc)
            Bq[ni][kc] = *(const f16x8*)(qbase + (size_t)(16*ni + l15) * DH
                                         + kc * 32 + quad * 8);

    f32x4 O[2][4] = {};                 // row q = 16mi+quad*4+reg, col d = 16ni+l15
    float m_run[2] = { -INFINITY, -INFINITY };
    float l_run[2] = { 0.0f, 0.0f };
    const float sc = 0.125f * L2E;      // scale folded with log2(e) (exp2 domain)

    for (int kt = 0; kt < NN / 64; ++kt) {
        __syncthreads();                // prior-iter Kh/Vt reads complete
        // Stage K tile (natural) and V tile (already transposed in global).
        #pragma unroll
        for (int i = 0; i < 2; ++i) {
            const int r = (tid >> 3) + 32 * i;
            const int c = (tid & 7) * 8;
            *(f16x8*)&Kh[r][c] = *(const f16x8*)(kbase + (size_t)(kt*64 + r) * DH + c);
            *(f16x8*)&Vt[r][c] = *(const f16x8*)(vtbase + (size_t)r * NN + kt*64 + c);
        }
        if (tid < 16) {
            f32x4 mv = *(const f32x4*)(mask + (size_t)b * NN + kt*64 + (tid << 2));
            mv *= L2E;
            *(f32x4*)&Msk[tid << 2] = mv;
        }
        __syncthreads();

        // S^T = K · Q^T : C-frags st[mi over keys][ni over q]
        f32x4 st[4][2] = {};
        #pragma unroll
        for (int mi = 0; mi < 4; ++mi) {
            f16x8 Ak0 = *(const f16x8*)&Kh[16*mi + l15][quad * 8];
            f16x8 Ak1 = *(const f16x8*)&Kh[16*mi + l15][32 + quad * 8];
            #pragma unroll
            for (int ni = 0; ni < 2; ++ni) {
                st[mi][ni] = __builtin_amdgcn_mfma_f32_16x16x32_f16(Ak0, Bq[ni][0], st[mi][ni], 0, 0, 0);
                st[mi][ni] = __builtin_amdgcn_mfma_f32_16x16x32_f16(Ak1, Bq[ni][1], st[mi][ni], 0, 0, 0);
            }
        }

        // mask (in exp2 domain) per key row
        f32x4 mskv[4];
        #pragma unroll
        for (int mi = 0; mi < 4; ++mi)
            mskv[mi] = *(const f32x4*)&Msk[16*mi + quad*4];

        float alpha[2];
        #pragma unroll
        for (int ni = 0; ni < 2; ++ni) {
            float mloc = -INFINITY;
            #pragma unroll
            for (int mi = 0; mi < 4; ++mi) {
                #pragma unroll
                for (int r = 0; r < 4; ++r) {
                    float s2 = st[mi][ni][r] * sc + mskv[mi][r];
                    st[mi][ni][r] = s2;
                    mloc = fmaxf(mloc, s2);
                }
            }
            mloc = fmaxf(mloc, __shfl_xor(mloc, 16));
            mloc = fmaxf(mloc, __shfl_xor(mloc, 32));
            const float mnew = fmaxf(m_run[ni], mloc);
            alpha[ni] = exp2f(m_run[ni] - mnew);
            m_run[ni] = mnew;
            float rsum = 0.0f;
            #pragma unroll
            for (int mi = 0; mi < 4; ++mi) {
                f16x4 ph;
                #pragma unroll
                for (int r = 0; r < 4; ++r) {
                    float p = exp2f(st[mi][ni][r] - mnew);
                    rsum += p;
                    ph[r] = (f16)p;
                }
                // P^T C-layout → Pt[q][key]: 4 regs are 4 consecutive keys
                *(f16x4*)&Pt[w][16*ni + l15][16*mi + quad*4] = ph;
            }
            rsum += __shfl_xor(rsum, 16);
            rsum += __shfl_xor(rsum, 32);
            l_run[ni] = l_run[ni] * alpha[ni] + rsum;
        }

        // Broadcast alpha from q=lane&15 mapping to q=quad*4+reg mapping.
        if (quad == 0) {
            Brd[w][l15]      = alpha[0];
            Brd[w][16 + l15] = alpha[1];
        }
        f32x4 av[2];
        #pragma unroll
        for (int mi = 0; mi < 2; ++mi)
            av[mi] = *(const f32x4*)&Brd[w][16*mi + quad*4];
        #pragma unroll
        for (int mi = 0; mi < 2; ++mi)
            #pragma unroll
            for (int ni = 0; ni < 4; ++ni)
                O[mi][ni] *= av[mi];

        // O += P · V  (A = Pt rows, B = Vt rows)
        f16x8 Bv[4][2];
        #pragma unroll
        for (int ni = 0; ni < 4; ++ni) {
            Bv[ni][0] = *(const f16x8*)&Vt[16*ni + l15][quad * 8];
            Bv[ni][1] = *(const f16x8*)&Vt[16*ni + l15][32 + quad * 8];
        }
        #pragma unroll
        for (int mi = 0; mi < 2; ++mi) {
            f16x8 Ap0 = *(const f16x8*)&Pt[w][16*mi + l15][quad * 8];
            f16x8 Ap1 = *(const f16x8*)&Pt[w][16*mi + l15][32 + quad * 8];
            #pragma unroll
            for (int ni = 0; ni < 4; ++ni) {
                O[mi][ni] = __builtin_amdgcn_mfma_f32_16x16x32_f16(Ap0, Bv[ni][0], O[mi][ni], 0, 0, 0);
                O[mi][ni] = __builtin_amdgcn_mfma_f32_16x16x32_f16(Ap1, Bv[ni][1], O[mi][ni], 0, 0, 0);
            }
        }
    }

    // Normalize: broadcast l through LDS (same mapping fix as alpha).
    if (quad == 0) {
        Brd[w][l15]      = l_run[0];
        Brd[w][16 + l15] = l_run[1];
    }
    #pragma unroll
    for (int mi = 0; mi < 2; ++mi) {
        f32x4 lv = *(const f32x4*)&Brd[w][16*mi + quad*4];
        f32x4 iv;
        #pragma unroll
        for (int r = 0; r < 4; ++r) iv[r] = 1.0f / lv[r];
        #pragma unroll
        for (int ni = 0; ni < 4; ++ni) {
            f32x4 o = O[mi][ni] * iv;
            #pragma unroll
            for (int r = 0; r < 4; ++r) {
                const int qrow = qt*128 + w*32 + 16*mi + quad*4 + r;
                out[((size_t)b * NN + qrow) * CC + h * DH + 16*ni + l15] = o[r];
            }
        }
    }
}

// ---------------------------------------------------------------------------
// Kernel 3: output projection GEMM (M=8192, N=512, K=512) + bias. fp32.
// ---------------------------------------------------------------------------
__global__ __launch_bounds__(256) void proj_kernel(
    const float* __restrict__ a, const float* __restrict__ W,
    const float* __restrict__ bias, float* __restrict__ out)
{
    __shared__ float As[16][68];
    __shared__ float Bs[16][68];
    const int m0 = blockIdx.x * 64;
    const int n0 = blockIdx.y * 64;
    const int tid = threadIdx.x;
    const int ty = tid >> 4, tx = tid & 15;
    const int lr = tid >> 2;
    const int lc = (tid & 3) << 2;

    float acc[4][4] = {};
    const float* arow = a + (size_t)(m0 + lr) * CC + lc;
    const float* wrow = W + (size_t)(n0 + lr) * CC + lc;

    for (int k0 = 0; k0 < CC; k0 += 16) {
        float4 a4 = *(const float4*)(arow + k0);
        float4 b4 = *(const float4*)(wrow + k0);
        As[lc+0][lr] = a4.x; As[lc+1][lr] = a4.y;
        As[lc+2][lr] = a4.z; As[lc+3][lr] = a4.w;
        Bs[lc+0][lr] = b4.x; Bs[lc+1][lr] = b4.y;
        Bs[lc+2][lr] = b4.z; Bs[lc+3][lr] = b4.w;
        __syncthreads();
        #pragma unroll
        for (int kk = 0; kk < 16; ++kk) {
            float4 av = *(const float4*)&As[kk][ty << 2];
            float4 bv = *(const float4*)&Bs[kk][tx << 2];
            float ar[4] = {av.x, av.y, av.z, av.w};
            float br[4] = {bv.x, bv.y, bv.z, bv.w};
            #pragma unroll
            for (int r = 0; r < 4; ++r)
                #pragma unroll
                for (int c = 0; c < 4; ++c)
                    acc[r][c] = fmaf(ar[r], br[c], acc[r][c]);
        }
        __syncthreads();
    }

    float4 bb = *(const float4*)(bias + n0 + (tx << 2));
    #pragma unroll
    for (int r = 0; r < 4; ++r) {
        const int m = m0 + (ty << 2) + r;
        float4 o = make_float4(acc[r][0] + bb.x, acc[r][1] + bb.y,
                               acc[r][2] + bb.z, acc[r][3] + bb.w);
        *(float4*)(out + (size_t)m * CC + n0 + (tx << 2)) = o;
    }
}

// ---------------------------------------------------------------------------
extern "C" void kernel_launch(void* const* d_in, const int* in_sizes, int n_in,
                              void* d_out, int out_size, void* d_ws, size_t ws_size,
                              hipStream_t stream)
{
    const float* x     = (const float*)d_in[0];
    const float* mask  = (const float*)d_in[1];
    const float* times = (const float*)d_in[2];
    const float* Wqkv  = (const float*)d_in[3];
    const float* Wproj = (const float*)d_in[4];
    const float* bproj = (const float*)d_in[5];
    const int*   ncls  = (const int*)d_in[6];
    float* out = (float*)d_out;

    const size_t per = (size_t)BB * HH * NN * DH;   // 4,194,304 elements
    f16* q  = (f16*)d_ws;
    f16* k  = q + per;
    f16* vt = k + per;
    float* ao = (float*)(vt + per);                 // attention out (B,N,C) fp32

    qkv_rope_kernel<<<dim3(MM / 64, QKV_N / 64), 256, 0, stream>>>(
        x, Wqkv, times, ncls, q, k, vt);
    attn_kernel<<<dim3(BB * HH, NN / 128), 256, 0, stream>>>(
        q, k, vt, mask, ao);
    proj_kernel<<<dim3(MM / 64, CC / 64), 256, 0, stream>>>(
        ao, Wproj, bproj, out);
}

// Round 3
// 203.450 us; speedup vs baseline: 4.1719x; 1.8689x over previous
//
#include <hip/hip_runtime.h>
#include <math.h>

// Problem constants (setup_inputs): B=4, N=2048, C=512, H=8, Dh=64
#define BB 4
#define NN 2048
#define CC 512
#define HH 8
#define DH 64
#define MM (BB*NN)          // 8192 rows
#define QKV_N (3*CC)        // 1536

typedef _Float16 f16;
typedef __attribute__((ext_vector_type(4))) _Float16 f16x4;
typedef __attribute__((ext_vector_type(8))) _Float16 f16x8;
typedef __attribute__((ext_vector_type(4))) float f32x4;

#define L2E 1.4426950408889634f

// async global->LDS, 16B per lane. LDS dest is wave-uniform base + lane*16,
// so LDS layout MUST be exact lane-order (no padding).
#define GL16(g, l) __builtin_amdgcn_global_load_lds(                       \
    (const __attribute__((address_space(1))) void*)(g),                    \
    (__attribute__((address_space(3))) void*)(l), 16, 0, 0)

// ---------------------------------------------------------------------------
// Kernel 0: cast x, Wqkv, Wproj to fp16 (vectorized, memory-bound).
// ---------------------------------------------------------------------------
#define SX4 (MM*CC/4)          // 1048576
#define SW4 (QKV_N*CC/4)       // 196608
#define SP4 (CC*CC/4)          // 65536
__global__ __launch_bounds__(256) void cast_kernel(
    const float* __restrict__ x, const float* __restrict__ wqkv,
    const float* __restrict__ wproj,
    f16* __restrict__ xh, f16* __restrict__ wqh, f16* __restrict__ wph)
{
    const int t = blockIdx.x * 256 + threadIdx.x;
    const float* src; f16* dst; int i;
    if (t < SX4)            { src = x;     dst = xh;  i = t; }
    else if (t < SX4 + SW4) { src = wqkv;  dst = wqh; i = t - SX4; }
    else                    { src = wproj; dst = wph; i = t - SX4 - SW4; }
    f32x4 v = *(const f32x4*)(src + 4 * (size_t)i);
    f16x4 h = { (f16)v[0], (f16)v[1], (f16)v[2], (f16)v[3] };
    *(f16x4*)(dst + 4 * (size_t)i) = h;
}

// ---------------------------------------------------------------------------
// Kernel 1: QKV GEMM, fp16 MFMA. M=8192, N=1536, K=512. 128x128 tile, BK=32,
// 4 waves in 2x2 grid, each wave 4x4 16x16 C-tiles. global_load_lds staging.
// Epilogue: q,k -> (B,H,N,Dh) fp16 ; v -> transposed (B,H,Dh,N) fp16.
// ---------------------------------------------------------------------------
__global__ __launch_bounds__(256) void qkv_gemm(
    const f16* __restrict__ xh, const f16* __restrict__ wh,
    f16* __restrict__ qo, f16* __restrict__ ko, f16* __restrict__ vto)
{
    __shared__ f16 As[128][32];
    __shared__ f16 Bs[128][32];
    const int m0 = blockIdx.x * 128;
    const int n0 = blockIdx.y * 128;
    const int tid = threadIdx.x;
    const int lane = tid & 63;
    const int w = tid >> 6;
    const int wm = (w & 1) * 64, wn = (w >> 1) * 64;
    const int l15 = lane & 15, quad = lane >> 4;

    const int sr = tid >> 2;           // staging row 0..63
    const int sc = (tid & 3) * 8;      // staging col (halves)
    const f16* ga0 = xh + (size_t)(m0 + sr) * CC + sc;
    const f16* ga1 = xh + (size_t)(m0 + sr + 64) * CC + sc;
    const f16* gb0 = wh + (size_t)(n0 + sr) * CC + sc;
    const f16* gb1 = wh + (size_t)(n0 + sr + 64) * CC + sc;
    f16* la0 = &As[sr][sc];      f16* la1 = &As[sr + 64][sc];
    f16* lb0 = &Bs[sr][sc];      f16* lb1 = &Bs[sr + 64][sc];

    f32x4 acc[4][4] = {};
    for (int k0 = 0; k0 < CC; k0 += 32) {
        __syncthreads();                 // prior-iter LDS reads done
        GL16(ga0 + k0, la0);
        GL16(ga1 + k0, la1);
        GL16(gb0 + k0, lb0);
        GL16(gb1 + k0, lb1);
        __syncthreads();                 // drains vmcnt (async->LDS visible)

        f16x8 af[4], bf[4];
        #pragma unroll
        for (int mi = 0; mi < 4; ++mi)
            af[mi] = *(const f16x8*)&As[wm + mi*16 + l15][quad * 8];
        #pragma unroll
        for (int ni = 0; ni < 4; ++ni)
            bf[ni] = *(const f16x8*)&Bs[wn + ni*16 + l15][quad * 8];
        #pragma unroll
        for (int mi = 0; mi < 4; ++mi)
            #pragma unroll
            for (int ni = 0; ni < 4; ++ni)
                acc[mi][ni] = __builtin_amdgcn_mfma_f32_16x16x32_f16(
                    af[mi], bf[ni], acc[mi][ni], 0, 0, 0);
    }

    // Epilogue. n0 is 128-aligned so 'which' is constant per block.
    const int which = n0 >> 9;          // 0=q, 1=k, 2=v
    const int b     = m0 >> 11;         // batch constant per block (128|2048)
    const int mloc  = m0 & (NN - 1);

    if (which == 2) {
        // v: store transposed (B,H,Dh,N): lane owns col d, 4 consecutive n.
        #pragma unroll
        for (int mi = 0; mi < 4; ++mi)
            #pragma unroll
            for (int ni = 0; ni < 4; ++ni) {
                const int cl = wn + ni*16 + l15;          // 0..127
                const int hh = ((n0 & 511) + cl) >> 6;
                const int d  = ((n0 & 511) + cl) & 63;
                const int n  = mloc + wm + mi*16 + quad*4;
                f16x4 pk = { (f16)acc[mi][ni][0], (f16)acc[mi][ni][1],
                             (f16)acc[mi][ni][2], (f16)acc[mi][ni][3] };
                *(f16x4*)(vto + ((size_t)(b*HH + hh) * DH + d) * NN + n) = pk;
            }
        return;
    }

    f16* dst = which ? ko : qo;
    #pragma unroll
    for (int mi = 0; mi < 4; ++mi)
        #pragma unroll
        for (int r = 0; r < 4; ++r) {
            const int n = mloc + wm + mi*16 + quad*4 + r;
            #pragma unroll
            for (int ni = 0; ni < 4; ++ni) {
                const int cl = wn + ni*16 + l15;
                const int hh = ((n0 & 511) + cl) >> 6;
                const int d  = ((n0 & 511) + cl) & 63;
                dst[((size_t)(b*HH + hh) * NN + n) * DH + d] = (f16)acc[mi][ni][r];
            }
        }
}

// ---------------------------------------------------------------------------
// Kernel 2: RoPE over q,k in place (B,H,N,Dh). Pairs are d-contiguous ->
// fully in-lane, no shuffles. One thread = 8 d's = 4 pairs, for q AND k.
// ---------------------------------------------------------------------------
__global__ __launch_bounds__(256) void rope_kernel(
    f16* __restrict__ q, f16* __restrict__ k,
    const float* __restrict__ times, const int* __restrict__ nclsp)
{
    const int t = blockIdx.x * 256 + threadIdx.x;    // 0 .. 524287
    const int row = t >> 3;                          // bh*2048 + n
    const int d0  = (t & 7) * 8;
    const int n   = row & (NN - 1);
    const int b   = row >> 14;                       // /(H*N)
    if (n < *nclsp) return;
    const float pos = rintf(times[b * NN + n] * 30.0f);   // MAX_FPS

    f16x8 qv = *(const f16x8*)(q + (size_t)row * DH + d0);
    f16x8 kv = *(const f16x8*)(k + (size_t)row * DH + d0);
    f16x8 qr, kr;
    #pragma unroll
    for (int p = 0; p < 4; ++p) {
        const int j = (d0 >> 1) + p;
        const float invf = exp2f((float)j * (-13.287712379549449f / 32.0f));
        float s, c;
        sincosf(pos * invf, &s, &c);
        const float q0 = (float)qv[2*p], q1 = (float)qv[2*p+1];
        qr[2*p]   = (f16)(q0 * c - q1 * s);
        qr[2*p+1] = (f16)(q0 * s + q1 * c);
        const float k0 = (float)kv[2*p], k1 = (float)kv[2*p+1];
        kr[2*p]   = (f16)(k0 * c - k1 * s);
        kr[2*p+1] = (f16)(k0 * s + k1 * c);
    }
    *(f16x8*)(q + (size_t)row * DH + d0) = qr;
    *(f16x8*)(k + (size_t)row * DH + d0) = kr;
}

// ---------------------------------------------------------------------------
// Kernel 3: fp16-MFMA flash attention (unchanged from R2 except fp16 output).
// ---------------------------------------------------------------------------
__global__ __launch_bounds__(256, 2) void attn_kernel(
    const f16* __restrict__ qg, const f16* __restrict__ kg,
    const f16* __restrict__ vtg, const float* __restrict__ mask,
    f16* __restrict__ out)
{
    __shared__ f16 Kh[64][72];      // [key][d]
    __shared__ f16 Vt[64][72];      // [d][key]
    __shared__ f16 Pt[4][32][72];   // per-wave [q][key]
    __shared__ float Msk[64];       // mask*log2e for current key tile
    __shared__ float Brd[4][32];    // per-wave alpha / l broadcast

    const int bh  = blockIdx.x;          // 0..31
    const int qt  = blockIdx.y;          // 0..15
    const int b   = bh >> 3;
    const int h   = bh & 7;
    const int tid = threadIdx.x;
    const int w    = tid >> 6;
    const int lane = tid & 63;
    const int l15  = lane & 15;
    const int quad = lane >> 4;

    const f16* qbase  = qg  + ((size_t)bh * NN + qt * 128 + w * 32) * DH;
    const f16* kbase  = kg  + (size_t)bh * NN * DH;
    const f16* vtbase = vtg + (size_t)bh * DH * NN;

    // Q B-fragments: persistent across the whole K loop.
    f16x8 Bq[2][2];
    #pragma unroll
    for (int ni = 0; ni < 2; ++ni)
        #pragma unroll
        for (int kc = 0; kc < 2; ++kc)
            Bq[ni][kc] = *(const f16x8*)(qbase + (size_t)(16*ni + l15) * DH
                                         + kc * 32 + quad * 8);

    f32x4 O[2][4] = {};
    float m_run[2] = { -INFINITY, -INFINITY };
    float l_run[2] = { 0.0f, 0.0f };
    const float sc = 0.125f * L2E;

    for (int kt = 0; kt < NN / 64; ++kt) {
        __syncthreads();
        #pragma unroll
        for (int i = 0; i < 2; ++i) {
            const int r = (tid >> 3) + 32 * i;
            const int c = (tid & 7) * 8;
            *(f16x8*)&Kh[r][c] = *(const f16x8*)(kbase + (size_t)(kt*64 + r) * DH + c);
            *(f16x8*)&Vt[r][c] = *(const f16x8*)(vtbase + (size_t)r * NN + kt*64 + c);
        }
        if (tid < 16) {
            f32x4 mv = *(const f32x4*)(mask + (size_t)b * NN + kt*64 + (tid << 2));
            mv *= L2E;
            *(f32x4*)&Msk[tid << 2] = mv;
        }
        __syncthreads();

        // S^T = K · Q^T
        f32x4 st[4][2] = {};
        #pragma unroll
        for (int mi = 0; mi < 4; ++mi) {
            f16x8 Ak0 = *(const f16x8*)&Kh[16*mi + l15][quad * 8];
            f16x8 Ak1 = *(const f16x8*)&Kh[16*mi + l15][32 + quad * 8];
            #pragma unroll
            for (int ni = 0; ni < 2; ++ni) {
                st[mi][ni] = __builtin_amdgcn_mfma_f32_16x16x32_f16(Ak0, Bq[ni][0], st[mi][ni], 0, 0, 0);
                st[mi][ni] = __builtin_amdgcn_mfma_f32_16x16x32_f16(Ak1, Bq[ni][1], st[mi][ni], 0, 0, 0);
            }
        }

        f32x4 mskv[4];
        #pragma unroll
        for (int mi = 0; mi < 4; ++mi)
            mskv[mi] = *(const f32x4*)&Msk[16*mi + quad*4];

        float alpha[2];
        #pragma unroll
        for (int ni = 0; ni < 2; ++ni) {
            float mloc = -INFINITY;
            #pragma unroll
            for (int mi = 0; mi < 4; ++mi) {
                #pragma unroll
                for (int r = 0; r < 4; ++r) {
                    float s2 = st[mi][ni][r] * sc + mskv[mi][r];
                    st[mi][ni][r] = s2;
                    mloc = fmaxf(mloc, s2);
                }
            }
            mloc = fmaxf(mloc, __shfl_xor(mloc, 16));
            mloc = fmaxf(mloc, __shfl_xor(mloc, 32));
            const float mnew = fmaxf(m_run[ni], mloc);
            alpha[ni] = exp2f(m_run[ni] - mnew);
            m_run[ni] = mnew;
            float rsum = 0.0f;
            #pragma unroll
            for (int mi = 0; mi < 4; ++mi) {
                f16x4 ph;
                #pragma unroll
                for (int r = 0; r < 4; ++r) {
                    float p = exp2f(st[mi][ni][r] - mnew);
                    rsum += p;
                    ph[r] = (f16)p;
                }
                *(f16x4*)&Pt[w][16*ni + l15][16*mi + quad*4] = ph;
            }
            rsum += __shfl_xor(rsum, 16);
            rsum += __shfl_xor(rsum, 32);
            l_run[ni] = l_run[ni] * alpha[ni] + rsum;
        }

        if (quad == 0) {
            Brd[w][l15]      = alpha[0];
            Brd[w][16 + l15] = alpha[1];
        }
        f32x4 av[2];
        #pragma unroll
        for (int mi = 0; mi < 2; ++mi)
            av[mi] = *(const f32x4*)&Brd[w][16*mi + quad*4];
        #pragma unroll
        for (int mi = 0; mi < 2; ++mi)
            #pragma unroll
            for (int ni = 0; ni < 4; ++ni)
                O[mi][ni] *= av[mi];

        // O += P · V
        f16x8 Bv[4][2];
        #pragma unroll
        for (int ni = 0; ni < 4; ++ni) {
            Bv[ni][0] = *(const f16x8*)&Vt[16*ni + l15][quad * 8];
            Bv[ni][1] = *(const f16x8*)&Vt[16*ni + l15][32 + quad * 8];
        }
        #pragma unroll
        for (int mi = 0; mi < 2; ++mi) {
            f16x8 Ap0 = *(const f16x8*)&Pt[w][16*mi + l15][quad * 8];
            f16x8 Ap1 = *(const f16x8*)&Pt[w][16*mi + l15][32 + quad * 8];
            #pragma unroll
            for (int ni = 0; ni < 4; ++ni) {
                O[mi][ni] = __builtin_amdgcn_mfma_f32_16x16x32_f16(Ap0, Bv[ni][0], O[mi][ni], 0, 0, 0);
                O[mi][ni] = __builtin_amdgcn_mfma_f32_16x16x32_f16(Ap1, Bv[ni][1], O[mi][ni], 0, 0, 0);
            }
        }
    }

    if (quad == 0) {
        Brd[w][l15]      = l_run[0];
        Brd[w][16 + l15] = l_run[1];
    }
    #pragma unroll
    for (int mi = 0; mi < 2; ++mi) {
        f32x4 lv = *(const f32x4*)&Brd[w][16*mi + quad*4];
        f32x4 iv;
        #pragma unroll
        for (int r = 0; r < 4; ++r) iv[r] = 1.0f / lv[r];
        #pragma unroll
        for (int ni = 0; ni < 4; ++ni) {
            f32x4 o = O[mi][ni] * iv;
            #pragma unroll
            for (int r = 0; r < 4; ++r) {
                const int qrow = qt*128 + w*32 + 16*mi + quad*4 + r;
                out[((size_t)b * NN + qrow) * CC + h * DH + 16*ni + l15] = (f16)o[r];
            }
        }
    }
}

// ---------------------------------------------------------------------------
// Kernel 4: proj GEMM, fp16 MFMA. M=8192, N=512, K=512. Same skeleton as
// qkv_gemm; fp32 output + bias.
// ---------------------------------------------------------------------------
__global__ __launch_bounds__(256) void proj_gemm(
    const f16* __restrict__ ah, const f16* __restrict__ wh,
    const float* __restrict__ bias, float* __restrict__ out)
{
    __shared__ f16 As[128][32];
    __shared__ f16 Bs[128][32];
    const int m0 = blockIdx.x * 128;
    const int n0 = blockIdx.y * 128;
    const int tid = threadIdx.x;
    const int lane = tid & 63;
    const int w = tid >> 6;
    const int wm = (w & 1) * 64, wn = (w >> 1) * 64;
    const int l15 = lane & 15, quad = lane >> 4;

    const int sr = tid >> 2;
    const int sc = (tid & 3) * 8;
    const f16* ga0 = ah + (size_t)(m0 + sr) * CC + sc;
    const f16* ga1 = ah + (size_t)(m0 + sr + 64) * CC + sc;
    const f16* gb0 = wh + (size_t)(n0 + sr) * CC + sc;
    const f16* gb1 = wh + (size_t)(n0 + sr + 64) * CC + sc;
    f16* la0 = &As[sr][sc];      f16* la1 = &As[sr + 64][sc];
    f16* lb0 = &Bs[sr][sc];      f16* lb1 = &Bs[sr + 64][sc];

    f32x4 acc[4][4] = {};
    for (int k0 = 0; k0 < CC; k0 += 32) {
        __syncthreads();
        GL16(ga0 + k0, la0);
        GL16(ga1 + k0, la1);
        GL16(gb0 + k0, lb0);
        GL16(gb1 + k0, lb1);
        __syncthreads();

        f16x8 af[4], bf[4];
        #pragma unroll
        for (int mi = 0; mi < 4; ++mi)
            af[mi] = *(const f16x8*)&As[wm + mi*16 + l15][quad * 8];
        #pragma unroll
        for (int ni = 0; ni < 4; ++ni)
            bf[ni] = *(const f16x8*)&Bs[wn + ni*16 + l15][quad * 8];
        #pragma unroll
        for (int mi = 0; mi < 4; ++mi)
            #pragma unroll
            for (int ni = 0; ni < 4; ++ni)
                acc[mi][ni] = __builtin_amdgcn_mfma_f32_16x16x32_f16(
                    af[mi], bf[ni], acc[mi][ni], 0, 0, 0);
    }

    float bb[4];
    #pragma unroll
    for (int ni = 0; ni < 4; ++ni)
        bb[ni] = bias[n0 + wn + ni*16 + l15];

    #pragma unroll
    for (int mi = 0; mi < 4; ++mi)
        #pragma unroll
        for (int r = 0; r < 4; ++r) {
            const int m = m0 + wm + mi*16 + quad*4 + r;
            #pragma unroll
            for (int ni = 0; ni < 4; ++ni)
                out[(size_t)m * CC + n0 + wn + ni*16 + l15] = acc[mi][ni][r] + bb[ni];
        }
}

// ---------------------------------------------------------------------------
extern "C" void kernel_launch(void* const* d_in, const int* in_sizes, int n_in,
                              void* d_out, int out_size, void* d_ws, size_t ws_size,
                              hipStream_t stream)
{
    const float* x     = (const float*)d_in[0];
    const float* mask  = (const float*)d_in[1];
    const float* times = (const float*)d_in[2];
    const float* Wqkv  = (const float*)d_in[3];
    const float* Wproj = (const float*)d_in[4];
    const float* bproj = (const float*)d_in[5];
    const int*   ncls  = (const int*)d_in[6];
    float* out = (float*)d_out;

    const size_t per = (size_t)BB * HH * NN * DH;   // 4,194,304 elements
    f16* xh  = (f16*)d_ws;                          // [8192][512]
    f16* wqh = xh + per;                            // [1536][512]
    f16* wph = wqh + (size_t)QKV_N * CC;            // [512][512]
    f16* q   = wph + (size_t)CC * CC;
    f16* k   = q + per;
    f16* vt  = k + per;
    f16* ao  = vt + per;                            // (B,N,C) fp16

    cast_kernel<<<(SX4 + SW4 + SP4) / 256, 256, 0, stream>>>(
        x, Wqkv, Wproj, xh, wqh, wph);
    qkv_gemm<<<dim3(MM / 128, QKV_N / 128), 256, 0, stream>>>(
        xh, wqh, q, k, vt);
    rope_kernel<<<(MM * HH * DH / 8) / 256, 256, 0, stream>>>(
        q, k, times, ncls);
    attn_kernel<<<dim3(BB * HH, NN / 128), 256, 0, stream>>>(
        q, k, vt, mask, ao);
    proj_gemm<<<dim3(MM / 128, CC / 128), 256, 0, stream>>>(
        ao, wph, bproj, out);
}